// Round 7
// baseline (297.731 us; speedup 1.0000x reference)
//
#include <hip/hip_runtime.h>

#define NODE 100
#define BATCH 64
#define DIM 128
#define IN_DIM 5
#define TOPK 30
#define INTER 256
#define NB (BATCH*NODE)   /* 6400 */
#define EPS 1e-5f
#define SLOPE 0.2f
#define REP 32
#define NBLK 256

// scratch float offsets
#define OFF_AGG    0
#define OFF_X3     819200
#define OFF_O1     1638400
#define OFF_U      3276800   /* u_i[0..4], u_j[5..9] */
#define OFF_EI     3276816   /* 100 (pad) */
#define OFF_EJ     3276928   /* 100 (pad) */
#define OFF_STATA  3277056   /* REP*32  : [rep*32+0..4]=S, [5..19]=M(ut) */
#define OFF_STAT2  3278080   /* REP*256 : sum[128], sq[128] */
#define OFF_STAT3  3286272   /* REP*512 : sum[256], sq[256] */
#define OFF_BAR    3302656   /* 16 ints (barrier counters) */
#define OFF_IDX    3302672   /* 3000 ints */
// memset-zero region: [OFF_STATA, OFF_BAR+16) floats
#define ZERO_BYTES ((OFF_BAR + 16 - OFF_STATA) * 4)

__device__ __forceinline__ void gbar(int* cnt) {
    __syncthreads();
    if (threadIdx.x == 0) {
        __threadfence();   // release: publish this block's writes device-wide
        __hip_atomic_fetch_add(cnt, 1, __ATOMIC_ACQ_REL, __HIP_MEMORY_SCOPE_AGENT);
        while (__hip_atomic_load(cnt, __ATOMIC_ACQUIRE, __HIP_MEMORY_SCOPE_AGENT) < NBLK) {
            __builtin_amdgcn_s_sleep(1);
        }
        __threadfence();   // acquire: invalidate stale cached lines
    }
    __syncthreads();
}

__global__ __launch_bounds__(256, 1) void k_fused(
        const float* __restrict__ x, const float* __restrict__ emb,
        const float* __restrict__ w_lin,
        const float* __restrict__ att_i, const float* __restrict__ att_j,
        const float* __restrict__ att_em_i, const float* __restrict__ att_em_j,
        const float* __restrict__ g_bias,
        const float* __restrict__ g1, const float* __restrict__ b1,
        const float* __restrict__ g2, const float* __restrict__ b2v,
        const float* __restrict__ g3, const float* __restrict__ b3,
        const float* __restrict__ w1, const float* __restrict__ b1v,
        const float* __restrict__ w2, const float* __restrict__ b2s,
        float* __restrict__ ws, int* __restrict__ idx, float* __restrict__ out) {
    __shared__ __align__(16) float smem[12928];
    int* bar = (int*)(ws + OFF_BAR);
    const int b = blockIdx.x, t = threadIdx.x, w = t >> 6, l = t & 63;
    const float invn = 1.f/(float)NB;

    // ================= phase 0: topk (b<25) / setup scalars (b==25) ========
    if (b < 25) {
        float* eT  = smem;           // [128][100]: eT[d*100+node]
        float* nsq = smem + 12800;
        for (int i = t; i < NODE*DIM; i += 256) {
            int node = i >> 7, d = i & 127;
            eT[d*NODE + node] = emb[i];
        }
        __syncthreads();
        if (t < NODE) {
            float s = 0.f;
            for (int d = 0; d < DIM; ++d) { float v = eT[d*NODE + t]; s += v*v; }
            nsq[t] = s;
        }
        __syncthreads();
        int i = b*4 + w;             // target node
        int j0 = l, j1 = l + 64;
        bool ok1 = (j1 < NODE);
        float d0 = 0.f, d1 = 0.f;
        for (int dd = 0; dd < DIM; ++dd) {
            float ei = eT[dd*NODE + i];
            d0 += ei * eT[dd*NODE + j0];
            if (ok1) d1 += ei * eT[dd*NODE + j1];
        }
        float sni = sqrtf(nsq[i]);
        float c0 = d0 / (sni * sqrtf(nsq[j0]));
        float c1 = ok1 ? d1 / (sni * sqrtf(nsq[j1])) : -INFINITY;
        for (int r = 0; r < TOPK; ++r) {
            float bv; int bi;
            if (c1 > c0) { bv = c1; bi = j1; } else { bv = c0; bi = j0; }
#pragma unroll
            for (int m = 32; m >= 1; m >>= 1) {
                float ov = __shfl_xor(bv, m, 64);
                int   oi = __shfl_xor(bi, m, 64);
                if (ov > bv || (ov == bv && oi < bi)) { bv = ov; bi = oi; }
            }
            if (l == 0) idx[i*TOPK + r] = bi;
            if (bi == j0) c0 = -INFINITY;
            if (bi == j1) c1 = -INFINITY;
        }
    } else if (b == 25) {
        float* Pi = smem;            // [5][128]
        float* Pj = smem + 640;
        if (t < DIM) {
            float wi = att_i[t], wj = att_j[t];
#pragma unroll
            for (int c = 0; c < IN_DIM; ++c) {
                float wl = w_lin[t*IN_DIM + c];
                Pi[c*128 + t] = wl*wi;
                Pj[c*128 + t] = wl*wj;
            }
        }
        __syncthreads();
        if (t < 10) {
            int c = (t < 5) ? t : t - 5;
            const float* P = (t < 5) ? Pi : Pj;
            float s = 0.f;
            for (int k = 0; k < DIM; ++k) s += P[c*128 + k];
            ws[OFF_U + t] = s;
        }
        float a0 = att_em_i[l], a1 = att_em_i[l+64];
        float b0 = att_em_j[l], b1v_ = att_em_j[l+64];
        for (int n = w*25; n < w*25 + 25; ++n) {
            float v0 = emb[n*DIM + l], v1 = emb[n*DIM + l + 64];
            float pi = v0*a0 + v1*a1;
            float pj = v0*b0 + v1*b1v_;
#pragma unroll
            for (int m = 32; m >= 1; m >>= 1) {
                pi += __shfl_xor(pi, m, 64);
                pj += __shfl_xor(pj, m, 64);
            }
            if (l == 0) { ws[OFF_EI + n] = pi; ws[OFF_EJ + n] = pj; }
        }
    }
    gbar(&bar[0]);

    // ================= phase 1: agg (5-dim attention) + bn1 moment sums ====
    {
        float* ul   = smem;               // 10
        float* xl   = smem + 16;          // [2][500]
        float* sjl  = smem + 1016;        // [2][100]
        int*   idl  = (int*)(smem + 1216);// [2][120]
        float* psum = smem + 1456;        // [4][20]
        float* agg  = ws + OFF_AGG;
        if (t < 10) ul[t] = ws[OFF_U + t];
        float wl0[IN_DIM], wl1[IN_DIM];
#pragma unroll
        for (int c = 0; c < IN_DIM; ++c) {
            wl0[c] = w_lin[l*IN_DIM + c];
            wl1[c] = w_lin[(l+64)*IN_DIM + c];
        }
        float gb0 = g_bias[l], gb1 = g_bias[l+64];
        float S0=0,S1=0,S2=0,S3=0,S4=0;
        float M[15];
#pragma unroll
        for (int m = 0; m < 15; ++m) M[m] = 0.f;
        int half = t >> 7, ht = t & 127, hw = (t >> 6) & 1;
        for (int v = b; v < 800; v += NBLK) {
            __syncthreads();
            int item = v*2 + half;
            int batch = item / 25;
            int nb0 = (item % 25) * 4;
            for (int i = ht; i < NODE*IN_DIM; i += 128) xl[half*500 + i] = x[batch*NODE*IN_DIM + i];
            for (int i = ht; i < 4*TOPK; i += 128) idl[half*120 + i] = idx[nb0*TOPK + i];
            __syncthreads();
            if (ht < NODE) {
                float s = ws[OFF_EJ + ht];
#pragma unroll
                for (int c = 0; c < IN_DIM; ++c) s += xl[half*500 + ht*IN_DIM + c] * ul[5 + c];
                sjl[half*100 + ht] = s;
            }
            __syncthreads();
            for (int lt = hw; lt < 4; lt += 2) {
                int node = nb0 + lt;
                int tgt = batch*NODE + node;
                float si = ws[OFF_EI + node];
#pragma unroll
                for (int c = 0; c < IN_DIM; ++c) si += xl[half*500 + node*IN_DIM + c] * ul[c];
                float mx = -INFINITY;
#pragma unroll
                for (int r = 0; r < TOPK; ++r) {
                    int s = idl[half*120 + lt*TOPK + r];
                    float a = si + sjl[half*100 + s];
                    a = (a > 0.f) ? a : SLOPE*a;
                    mx = fmaxf(mx, a);
                }
                float ssum = 0.f, x0=0,x1=0,x2=0,x3v=0,x4=0;
#pragma unroll
                for (int r = 0; r < TOPK; ++r) {
                    int s = idl[half*120 + lt*TOPK + r];
                    float a = si + sjl[half*100 + s];
                    a = (a > 0.f) ? a : SLOPE*a;
                    float e = expf(a - mx);
                    ssum += e;
                    const float* xr = &xl[half*500 + s*IN_DIM];
                    x0 += e*xr[0]; x1 += e*xr[1]; x2 += e*xr[2]; x3v += e*xr[3]; x4 += e*xr[4];
                }
                float inv = 1.f/(ssum + 1e-16f);
                float y0=x0*inv, y1=x1*inv, y2=x2*inv, y3=x3v*inv, y4=x4*inv;
                float o0 = y0*wl0[0]+y1*wl0[1]+y2*wl0[2]+y3*wl0[3]+y4*wl0[4] + gb0;
                float o1 = y0*wl1[0]+y1*wl1[1]+y2*wl1[2]+y3*wl1[3]+y4*wl1[4] + gb1;
                agg[tgt*DIM + l]      = o0;
                agg[tgt*DIM + l + 64] = o1;
                S0+=y0; S1+=y1; S2+=y2; S3+=y3; S4+=y4;
                M[0]+=y0*y0; M[1]+=y0*y1; M[2]+=y0*y2; M[3]+=y0*y3; M[4]+=y0*y4;
                M[5]+=y1*y1; M[6]+=y1*y2; M[7]+=y1*y3; M[8]+=y1*y4;
                M[9]+=y2*y2; M[10]+=y2*y3; M[11]+=y2*y4;
                M[12]+=y3*y3; M[13]+=y3*y4; M[14]+=y4*y4;
            }
        }
        __syncthreads();
        if (l == 0) {
            psum[w*20+0]=S0; psum[w*20+1]=S1; psum[w*20+2]=S2; psum[w*20+3]=S3; psum[w*20+4]=S4;
#pragma unroll
            for (int m = 0; m < 15; ++m) psum[w*20+5+m] = M[m];
        }
        __syncthreads();
        if (t < 20) {
            float p = psum[t] + psum[20+t] + psum[40+t] + psum[60+t];
            atomicAdd(&ws[OFF_STATA + (b & (REP-1))*32 + t], p);
        }
    }
    gbar(&bar[1]);

    // ================= phase 2: x3 = relu(bn1(agg))*emb + bn2 sums =========
    {
        float* A  = smem;            // 20
        float* pv = smem + 32;       // [8][128]
        float* pq = smem + 1056;     // [8][128]
        if (t < 20) {
            float s = 0.f;
#pragma unroll
            for (int r = 0; r < REP; ++r) s += ws[OFF_STATA + r*32 + t];
            A[t] = s;
        }
        __syncthreads();
        int cq = (t & 31) * 4;
        float muq[4], rsg[4], bq[4];
#pragma unroll
        for (int q = 0; q < 4; ++q) {
            int c = cq + q;
            float w0 = w_lin[c*IN_DIM+0], w1v = w_lin[c*IN_DIM+1], w2v = w_lin[c*IN_DIM+2],
                  w3 = w_lin[c*IN_DIM+3], w4 = w_lin[c*IN_DIM+4];
            float Sv = A[0]*w0 + A[1]*w1v + A[2]*w2v + A[3]*w3 + A[4]*w4;
            float Q  = w0*w0*A[5] + w1v*w1v*A[10] + w2v*w2v*A[14] + w3*w3*A[17] + w4*w4*A[19]
                     + 2.f*(w0*w1v*A[6] + w0*w2v*A[7] + w0*w3*A[8] + w0*w4*A[9]
                          + w1v*w2v*A[11] + w1v*w3*A[12] + w1v*w4*A[13]
                          + w2v*w3*A[15] + w2v*w4*A[16] + w3*w4*A[18]);
            float mv = Sv*invn;
            float mu = mv + g_bias[c];
            float var = fmaxf(Q*invn - mv*mv, 0.f);
            float rs = rsqrtf(var + EPS);
            muq[q] = mu; rsg[q] = rs*g1[c]; bq[q] = b1[c];
        }
        const float4* agg4 = (const float4*)(ws + OFF_AGG);
        const float4* emb4 = (const float4*)emb;
        float4* x34 = (float4*)(ws + OFF_X3);
        float a1[4] = {0,0,0,0}, a2[4] = {0,0,0,0};
        for (int v = b; v < 800; v += NBLK) {
            int i4 = v*256 + t;
            int row = i4 >> 5;
            int node = row % NODE;
            float4 av = agg4[i4];
            float4 ev = emb4[node*32 + (t & 31)];
            float o[4];
#pragma unroll
            for (int q = 0; q < 4; ++q) {
                float val = (((const float*)&av)[q] - muq[q])*rsg[q] + bq[q];
                val = fmaxf(val, 0.f);
                o[q] = val * ((const float*)&ev)[q];
                a1[q] += o[q];
                a2[q] += o[q]*o[q];
            }
            x34[i4] = make_float4(o[0], o[1], o[2], o[3]);
        }
        int g = t >> 5;
        *(float4*)&pv[g*128 + cq] = make_float4(a1[0], a1[1], a1[2], a1[3]);
        *(float4*)&pq[g*128 + cq] = make_float4(a2[0], a2[1], a2[2], a2[3]);
        __syncthreads();
        if (t < DIM) {
            float s1 = 0.f, s2 = 0.f;
#pragma unroll
            for (int r = 0; r < 8; ++r) { s1 += pv[r*128 + t]; s2 += pq[r*128 + t]; }
            int rep = b & (REP-1);
            atomicAdd(&ws[OFF_STAT2 + rep*256 + t], s1);
            atomicAdd(&ws[OFF_STAT2 + rep*256 + DIM + t], s2);
        }
    }
    gbar(&bar[2]);

    // ================= phase 3: o1 = relu(bn2(x3)) @ w1^T + b1 + bn3 sums ==
    if (b < 200) {
        float* aT     = smem;          // [32][36]
        float* wT     = smem + 1152;   // [32][260]
        float* ps     = smem + 9472;   // [4][256]
        float* ps2    = smem + 10496;  // [4][256]
        float* bn2raw = smem + 11520;  // 256
        float* mu2l   = smem + 11776;  // 128
        float* rs2l   = smem + 11904;  // 128
        {
            float s = 0.f;
#pragma unroll
            for (int r = 0; r < REP; ++r) s += ws[OFF_STAT2 + r*256 + t];
            bn2raw[t] = s;
        }
        __syncthreads();
        if (t < DIM) {
            float mu = bn2raw[t]*invn;
            float var = fmaxf(bn2raw[DIM + t]*invn - mu*mu, 0.f);
            mu2l[t] = mu;
            rs2l[t] = rsqrtf(var + EPS);
        }
        __syncthreads();
        const float* x3 = ws + OFF_X3;
        float* o1 = ws + OFF_O1;
        int r0 = b * 32;
        int cg = t & 63;
        int rg = t >> 6;
        float acc[8][4];
#pragma unroll
        for (int a = 0; a < 8; ++a)
#pragma unroll
            for (int q = 0; q < 4; ++q) acc[a][q] = 0.f;
        int kk = t & 31;
        for (int k0 = 0; k0 < DIM; k0 += 32) {
            int k = k0 + kk;
            float mu = mu2l[k], rs = rs2l[k], gg = g2[k], bb = b2v[k];
#pragma unroll
            for (int j = 0; j < 4; ++j) {
                int row = (t >> 5) + j*8;
                float v = (x3[(r0+row)*DIM + k] - mu)*rs*gg + bb;
                aT[row*36 + kk] = fmaxf(v, 0.f);
            }
#pragma unroll
            for (int j = 0; j < 32; ++j) {
                int i = t + j*256;
                int kk2 = i & 31, c = i >> 5;
                wT[kk2*260 + c] = w1[c*DIM + k0 + kk2];
            }
            __syncthreads();
#pragma unroll
            for (int q4 = 0; q4 < 8; ++q4) {
                float4 av[8], wv[4];
#pragma unroll
                for (int rr = 0; rr < 8; ++rr)
                    av[rr] = *(const float4*)&aT[(rg*8+rr)*36 + q4*4];
#pragma unroll
                for (int q = 0; q < 4; ++q)
                    wv[q] = *(const float4*)&wT[(q4*4+q)*260 + cg*4];
#pragma unroll
                for (int rr = 0; rr < 8; ++rr) {
                    acc[rr][0] += av[rr].x*wv[0].x + av[rr].y*wv[1].x + av[rr].z*wv[2].x + av[rr].w*wv[3].x;
                    acc[rr][1] += av[rr].x*wv[0].y + av[rr].y*wv[1].y + av[rr].z*wv[2].y + av[rr].w*wv[3].y;
                    acc[rr][2] += av[rr].x*wv[0].z + av[rr].y*wv[1].z + av[rr].z*wv[2].z + av[rr].w*wv[3].z;
                    acc[rr][3] += av[rr].x*wv[0].w + av[rr].y*wv[1].w + av[rr].z*wv[2].w + av[rr].w*wv[3].w;
                }
            }
            __syncthreads();
        }
        int cbase = cg*4;
        float4 bv = *(const float4*)&b1v[cbase];
        float lv[4]  = {0,0,0,0};
        float lv2[4] = {0,0,0,0};
#pragma unroll
        for (int rr = 0; rr < 8; ++rr) {
            int row = r0 + rg*8 + rr;
            float o0 = acc[rr][0] + bv.x;
            float o1v = acc[rr][1] + bv.y;
            float o2 = acc[rr][2] + bv.z;
            float o3 = acc[rr][3] + bv.w;
            *(float4*)&o1[row*INTER + cbase] = make_float4(o0, o1v, o2, o3);
            lv[0]+=o0;  lv2[0]+=o0*o0;
            lv[1]+=o1v; lv2[1]+=o1v*o1v;
            lv[2]+=o2;  lv2[2]+=o2*o2;
            lv[3]+=o3;  lv2[3]+=o3*o3;
        }
        *(float4*)&ps[rg*256 + cbase]  = make_float4(lv[0], lv[1], lv[2], lv[3]);
        *(float4*)&ps2[rg*256 + cbase] = make_float4(lv2[0], lv2[1], lv2[2], lv2[3]);
        __syncthreads();
        if (t < INTER) {
            float s1 = ps[t] + ps[256+t] + ps[512+t] + ps[768+t];
            float s2 = ps2[t] + ps2[256+t] + ps2[512+t] + ps2[768+t];
            int rep = b & (REP-1);
            atomicAdd(&ws[OFF_STAT3 + rep*512 + t], s1);
            atomicAdd(&ws[OFF_STAT3 + rep*512 + INTER + t], s2);
        }
    }
    gbar(&bar[3]);

    // ================= phase 4: out = relu(bn3(o1)) @ w2^T + b2 ============
    {
        float* raw  = smem;          // 512
        float* mu3l = smem + 512;    // 256
        float* rs3l = smem + 768;    // 256
        for (int tt = t; tt < 512; tt += 256) {
            float s = 0.f;
#pragma unroll
            for (int r = 0; r < REP; ++r) s += ws[OFF_STAT3 + r*512 + tt];
            raw[tt] = s;
        }
        __syncthreads();
        {
            float mu = raw[t]*invn;
            float var = fmaxf(raw[256 + t]*invn - mu*mu, 0.f);
            mu3l[t] = mu;
            rs3l[t] = rsqrtf(var + EPS);
        }
        __syncthreads();
        float m3[4], rg3[4], b3q[4], w2q[4];
#pragma unroll
        for (int q = 0; q < 4; ++q) {
            int c = l*4 + q;
            m3[q] = mu3l[c];
            rg3[q] = rs3l[c]*g3[c];
            b3q[q] = b3[c];
            w2q[q] = w2[c];
        }
        float bias2 = b2s[0];
        const float4* o14 = (const float4*)(ws + OFF_O1);
        for (int v = b; v < 1600; v += NBLK) {
            int row = v*4 + w;
            float4 vv = o14[row*64 + l];
            float s = 0.f;
#pragma unroll
            for (int q = 0; q < 4; ++q) {
                float val = (((const float*)&vv)[q] - m3[q])*rg3[q] + b3q[q];
                val = fmaxf(val, 0.f);
                s += val * w2q[q];
            }
#pragma unroll
            for (int m = 32; m >= 1; m >>= 1) s += __shfl_xor(s, m, 64);
            if (l == 0) out[row] = s + bias2;
        }
    }
}

extern "C" void kernel_launch(void* const* d_in, const int* in_sizes, int n_in,
                              void* d_out, int out_size, void* d_ws, size_t ws_size,
                              hipStream_t stream) {
    const float* x        = (const float*)d_in[0];
    const float* emb      = (const float*)d_in[1];
    const float* w_lin    = (const float*)d_in[2];
    const float* att_i    = (const float*)d_in[3];
    const float* att_j    = (const float*)d_in[4];
    const float* att_em_i = (const float*)d_in[5];
    const float* att_em_j = (const float*)d_in[6];
    const float* g_bias   = (const float*)d_in[7];
    const float* bn1_g    = (const float*)d_in[8];
    const float* bn1_b    = (const float*)d_in[9];
    const float* bn2_g    = (const float*)d_in[10];
    const float* bn2_b    = (const float*)d_in[11];
    const float* bn3_g    = (const float*)d_in[12];
    const float* bn3_b    = (const float*)d_in[13];
    const float* w1       = (const float*)d_in[14];
    const float* b1       = (const float*)d_in[15];
    const float* w2       = (const float*)d_in[16];
    const float* b2       = (const float*)d_in[17];
    float* out = (float*)d_out;
    float* ws  = (float*)d_ws;
    int*   idx = (int*)(ws + OFF_IDX);

    // zero stat accumulators + grid-barrier counters (graph-capturable)
    hipMemsetAsync((void*)(ws + OFF_STATA), 0, ZERO_BYTES, stream);

    k_fused<<<NBLK, 256, 0, stream>>>(x, emb, w_lin, att_i, att_j, att_em_i,
                                      att_em_j, g_bias, bn1_g, bn1_b, bn2_g, bn2_b,
                                      bn3_g, bn3_b, w1, b1, w2, b2, ws, idx, out);
}

// Round 8
// 222.051 us; speedup vs baseline: 1.3408x; 1.3408x over previous
//
#include <hip/hip_runtime.h>

#define NODE 100
#define BATCH 64
#define DIM 128
#define IN_DIM 5
#define TOPK 30
#define INTER 256
#define NB (BATCH*NODE)   /* 6400 */
#define EPS 1e-5f
#define SLOPE 0.2f
#define REP 8             /* stat replicas */
#define NBLK 400          /* blocks; block b owns rows [16b,16b+16) */
#define ROWS 16

// scratch float offsets
#define OFF_AGG    0
#define OFF_X3     819200
#define OFF_O1     1638400
#define OFF_U      3276800   /* u_i[0..4], u_j[5..9] */
#define OFF_EI     3276816   /* 100 (pad) */
#define OFF_EJ     3276928   /* 100 (pad) */
#define OFF_STATA  3277056   /* REP*32 */
#define OFF_STAT2  3277312   /* REP*256 */
#define OFF_STAT3  3279360   /* REP*512 */
#define OFF_BAR    3283456   /* 16 ints */
#define OFF_IDX    3283472   /* 3000 ints */
#define ZERO_BYTES ((OFF_IDX - OFF_STATA) * 4)

// ---- fine-grained agent-coherent accessors (no cache-wide maintenance) ----
__device__ __forceinline__ float aload(const float* p) {
    return __hip_atomic_load(p, __ATOMIC_RELAXED, __HIP_MEMORY_SCOPE_AGENT);
}
__device__ __forceinline__ void astore(float* p, float v) {
    __hip_atomic_store(p, v, __ATOMIC_RELAXED, __HIP_MEMORY_SCOPE_AGENT);
}
__device__ __forceinline__ int aloadi(const int* p) {
    return __hip_atomic_load(p, __ATOMIC_RELAXED, __HIP_MEMORY_SCOPE_AGENT);
}
__device__ __forceinline__ void astorei(int* p, int v) {
    __hip_atomic_store(p, v, __ATOMIC_RELAXED, __HIP_MEMORY_SCOPE_AGENT);
}

// grid barrier: no fences — all cross-block data flows via agent atomics.
__device__ __forceinline__ void gbar(int* cnt) {
    __syncthreads();
    if (threadIdx.x == 0) {
        __hip_atomic_fetch_add(cnt, 1, __ATOMIC_RELAXED, __HIP_MEMORY_SCOPE_AGENT);
        while (__hip_atomic_load(cnt, __ATOMIC_RELAXED, __HIP_MEMORY_SCOPE_AGENT) < NBLK)
            __builtin_amdgcn_s_sleep(2);
    }
    __syncthreads();
}

__global__ __launch_bounds__(256, 2) void k_fused(
        const float* __restrict__ x, const float* __restrict__ emb,
        const float* __restrict__ w_lin,
        const float* __restrict__ att_i, const float* __restrict__ att_j,
        const float* __restrict__ att_em_i, const float* __restrict__ att_em_j,
        const float* __restrict__ g_bias,
        const float* __restrict__ g1, const float* __restrict__ b1,
        const float* __restrict__ g2, const float* __restrict__ b2v,
        const float* __restrict__ g3, const float* __restrict__ b3,
        const float* __restrict__ w1, const float* __restrict__ b1v,
        const float* __restrict__ w2, const float* __restrict__ b2s,
        float* __restrict__ ws, int* __restrict__ idx, float* __restrict__ out) {
    __shared__ __align__(16) float smem[11456];   // 45.8 KB (max over phases)
    int* bar = (int*)(ws + OFF_BAR);
    const int b = blockIdx.x, t = threadIdx.x, w = t >> 6, l = t & 63;
    const float invn = 1.f/(float)NB;
    const int r0 = b * ROWS;

    // ===== phase 0: topk (b<25, dim-chunked LDS) / scalars (b==25) =========
    if (b < 25) {
        float* eT = smem;                  // [32][101] chunk, pad-101 => conflict-free
        int i = b*4 + w;                   // target node
        int j0 = l, j1 = l + 64;
        bool ok1 = (j1 < NODE);
        float d0 = 0.f, d1 = 0.f, ni = 0.f, n0 = 0.f, n1 = 0.f;
        for (int kc = 0; kc < 4; ++kc) {
            __syncthreads();
            for (int ii = t; ii < 3200; ii += 256) {
                int n = ii >> 5, d = ii & 31;
                eT[d*101 + n] = emb[n*DIM + kc*32 + d];
            }
            __syncthreads();
#pragma unroll
            for (int dd = 0; dd < 32; ++dd) {
                float ei = eT[dd*101 + i];
                float a0 = eT[dd*101 + j0];
                ni += ei*ei; d0 += ei*a0; n0 += a0*a0;
                if (ok1) { float a1v = eT[dd*101 + j1]; d1 += ei*a1v; n1 += a1v*a1v; }
            }
        }
        float sni = sqrtf(ni);
        float c0 = d0 / (sni * sqrtf(n0));
        float c1 = ok1 ? d1 / (sni * sqrtf(n1)) : -INFINITY;
        for (int r = 0; r < TOPK; ++r) {
            float bv; int bi;
            if (c1 > c0) { bv = c1; bi = j1; } else { bv = c0; bi = j0; }
#pragma unroll
            for (int m = 32; m >= 1; m >>= 1) {
                float ov = __shfl_xor(bv, m, 64);
                int   oi = __shfl_xor(bi, m, 64);
                if (ov > bv || (ov == bv && oi < bi)) { bv = ov; bi = oi; }
            }
            if (l == 0) astorei(idx + i*TOPK + r, bi);
            if (bi == j0) c0 = -INFINITY;
            if (bi == j1) c1 = -INFINITY;
        }
    } else if (b == 25) {
        float* Pi = smem;            // [5][128]
        float* Pj = smem + 640;
        if (t < DIM) {
            float wi = att_i[t], wj = att_j[t];
#pragma unroll
            for (int c = 0; c < IN_DIM; ++c) {
                float wl = w_lin[t*IN_DIM + c];
                Pi[c*128 + t] = wl*wi;
                Pj[c*128 + t] = wl*wj;
            }
        }
        __syncthreads();
        if (t < 10) {
            int c = (t < 5) ? t : t - 5;
            const float* P = (t < 5) ? Pi : Pj;
            float s = 0.f;
            for (int k = 0; k < DIM; ++k) s += P[c*128 + k];
            astore(ws + OFF_U + t, s);
        }
        float a0 = att_em_i[l], a1 = att_em_i[l+64];
        float b0 = att_em_j[l], b1v_ = att_em_j[l+64];
        for (int n = w*25; n < w*25 + 25; ++n) {
            float v0 = emb[n*DIM + l], v1 = emb[n*DIM + l + 64];
            float pi = v0*a0 + v1*a1;
            float pj = v0*b0 + v1*b1v_;
#pragma unroll
            for (int m = 32; m >= 1; m >>= 1) {
                pi += __shfl_xor(pi, m, 64);
                pj += __shfl_xor(pj, m, 64);
            }
            if (l == 0) { astore(ws + OFF_EI + n, pi); astore(ws + OFF_EJ + n, pj); }
        }
    }
    gbar(&bar[0]);

    // ===== phase 1: agg rows [r0,r0+16) (5-dim attention) + bn1 moments ====
    {
        float* ul   = smem;                // 16 (10 used)
        float* xl   = smem + 16;           // [2][500]
        float* sjl  = smem + 1016;         // [2][100]
        float* eil  = smem + 1216;         // [16]
        int*   idl  = (int*)(smem + 1232); // [16][30]
        float* psum = smem + 1712;         // [4][20]
        float* agg  = ws + OFF_AGG;
        int fb = r0 / NODE, lb = (r0 + ROWS - 1) / NODE;
        if (t < 10) ul[t] = aload(ws + OFF_U + t);
        for (int i = t; i < NODE*IN_DIM; i += 256) {
            xl[i]       = x[fb*NODE*IN_DIM + i];
            xl[500 + i] = x[lb*NODE*IN_DIM + i];
        }
        if (t < ROWS) eil[t] = aload(ws + OFF_EI + (r0 + t) % NODE);
        for (int i = t; i < ROWS*TOPK; i += 256) {
            int rr = i / TOPK;
            int node = (r0 + rr) % NODE;
            idl[i] = aloadi(idx + node*TOPK + (i % TOPK));
        }
        __syncthreads();
        if (t < 200) {
            int bb = t / 100, n = t % 100;
            float s = aload(ws + OFF_EJ + n);
#pragma unroll
            for (int c = 0; c < IN_DIM; ++c) s += xl[bb*500 + n*IN_DIM + c] * ul[5 + c];
            sjl[t] = s;
        }
        __syncthreads();
        float wl0[IN_DIM], wl1[IN_DIM];
#pragma unroll
        for (int c = 0; c < IN_DIM; ++c) {
            wl0[c] = w_lin[l*IN_DIM + c];
            wl1[c] = w_lin[(l+64)*IN_DIM + c];
        }
        float gb0 = g_bias[l], gb1 = g_bias[l+64];
        float S0=0,S1=0,S2=0,S3=0,S4=0;
        float M[15];
#pragma unroll
        for (int m = 0; m < 15; ++m) M[m] = 0.f;
        for (int rr = w; rr < ROWS; rr += 4) {
            int row = r0 + rr;
            int bb = (row / NODE == fb) ? 0 : 1;
            int node = row % NODE;
            float si = eil[rr];
#pragma unroll
            for (int c = 0; c < IN_DIM; ++c) si += xl[bb*500 + node*IN_DIM + c] * ul[c];
            float mx = -INFINITY;
#pragma unroll
            for (int r = 0; r < TOPK; ++r) {
                int s = idl[rr*TOPK + r];
                float a = si + sjl[bb*100 + s];
                a = (a > 0.f) ? a : SLOPE*a;
                mx = fmaxf(mx, a);
            }
            float ssum = 0.f, x0=0,x1=0,x2=0,x3v=0,x4=0;
#pragma unroll
            for (int r = 0; r < TOPK; ++r) {
                int s = idl[rr*TOPK + r];
                float a = si + sjl[bb*100 + s];
                a = (a > 0.f) ? a : SLOPE*a;
                float e = expf(a - mx);
                ssum += e;
                const float* xr = &xl[bb*500 + s*IN_DIM];
                x0 += e*xr[0]; x1 += e*xr[1]; x2 += e*xr[2]; x3v += e*xr[3]; x4 += e*xr[4];
            }
            float inv = 1.f/(ssum + 1e-16f);
            float y0=x0*inv, y1=x1*inv, y2=x2*inv, y3=x3v*inv, y4=x4*inv;
            float o0 = y0*wl0[0]+y1*wl0[1]+y2*wl0[2]+y3*wl0[3]+y4*wl0[4] + gb0;
            float o1 = y0*wl1[0]+y1*wl1[1]+y2*wl1[2]+y3*wl1[3]+y4*wl1[4] + gb1;
            agg[row*DIM + l]      = o0;
            agg[row*DIM + l + 64] = o1;
            S0+=y0; S1+=y1; S2+=y2; S3+=y3; S4+=y4;
            M[0]+=y0*y0; M[1]+=y0*y1; M[2]+=y0*y2; M[3]+=y0*y3; M[4]+=y0*y4;
            M[5]+=y1*y1; M[6]+=y1*y2; M[7]+=y1*y3; M[8]+=y1*y4;
            M[9]+=y2*y2; M[10]+=y2*y3; M[11]+=y2*y4;
            M[12]+=y3*y3; M[13]+=y3*y4; M[14]+=y4*y4;
        }
        __syncthreads();
        if (l == 0) {
            psum[w*20+0]=S0; psum[w*20+1]=S1; psum[w*20+2]=S2; psum[w*20+3]=S3; psum[w*20+4]=S4;
#pragma unroll
            for (int m = 0; m < 15; ++m) psum[w*20+5+m] = M[m];
        }
        __syncthreads();
        if (t < 20) {
            float p = psum[t] + psum[20+t] + psum[40+t] + psum[60+t];
            atomicAdd(&ws[OFF_STATA + (b & (REP-1))*32 + t], p);
        }
    }
    gbar(&bar[1]);

    // ===== phase 2: x3 rows [r0,r0+16) = relu(bn1(agg))*emb + bn2 sums =====
    {
        float* A  = smem;            // 20
        float* pv = smem + 32;       // [8][128]
        float* pq = smem + 1056;     // [8][128]
        if (t < 20) {
            float s = 0.f;
#pragma unroll
            for (int r = 0; r < REP; ++r) s += aload(ws + OFF_STATA + r*32 + t);
            A[t] = s;
        }
        __syncthreads();
        int cq = (t & 31) * 4;
        float muq[4], rsg[4], bq[4];
#pragma unroll
        for (int q = 0; q < 4; ++q) {
            int c = cq + q;
            float w0 = w_lin[c*IN_DIM+0], w1v = w_lin[c*IN_DIM+1], w2v = w_lin[c*IN_DIM+2],
                  w3 = w_lin[c*IN_DIM+3], w4 = w_lin[c*IN_DIM+4];
            float Sv = A[0]*w0 + A[1]*w1v + A[2]*w2v + A[3]*w3 + A[4]*w4;
            float Q  = w0*w0*A[5] + w1v*w1v*A[10] + w2v*w2v*A[14] + w3*w3*A[17] + w4*w4*A[19]
                     + 2.f*(w0*w1v*A[6] + w0*w2v*A[7] + w0*w3*A[8] + w0*w4*A[9]
                          + w1v*w2v*A[11] + w1v*w3*A[12] + w1v*w4*A[13]
                          + w2v*w3*A[15] + w2v*w4*A[16] + w3*w4*A[18]);
            float mv = Sv*invn;
            float mu = mv + g_bias[c];
            float var = fmaxf(Q*invn - mv*mv, 0.f);
            float rs = rsqrtf(var + EPS);
            muq[q] = mu; rsg[q] = rs*g1[c]; bq[q] = b1[c];
        }
        const float4* agg4 = (const float4*)(ws + OFF_AGG);
        const float4* emb4 = (const float4*)emb;
        float4* x34 = (float4*)(ws + OFF_X3);
        float a1[4] = {0,0,0,0}, a2[4] = {0,0,0,0};
#pragma unroll
        for (int p = 0; p < 2; ++p) {
            int i4 = b*512 + p*256 + t;
            int row = i4 >> 5;
            int node = row % NODE;
            float4 av = agg4[i4];
            float4 ev = emb4[node*32 + (t & 31)];
            float o[4];
#pragma unroll
            for (int q = 0; q < 4; ++q) {
                float val = (((const float*)&av)[q] - muq[q])*rsg[q] + bq[q];
                val = fmaxf(val, 0.f);
                o[q] = val * ((const float*)&ev)[q];
                a1[q] += o[q];
                a2[q] += o[q]*o[q];
            }
            x34[i4] = make_float4(o[0], o[1], o[2], o[3]);
        }
        int g = t >> 5;
        *(float4*)&pv[g*128 + cq] = make_float4(a1[0], a1[1], a1[2], a1[3]);
        *(float4*)&pq[g*128 + cq] = make_float4(a2[0], a2[1], a2[2], a2[3]);
        __syncthreads();
        if (t < DIM) {
            float s1 = 0.f, s2 = 0.f;
#pragma unroll
            for (int r = 0; r < 8; ++r) { s1 += pv[r*128 + t]; s2 += pq[r*128 + t]; }
            atomicAdd(&ws[OFF_STAT2 + (b & (REP-1))*256 + t], s1);
            atomicAdd(&ws[OFF_STAT2 + (b & (REP-1))*256 + DIM + t], s2);
        }
    }
    gbar(&bar[2]);

    // ===== phase 3: o1 rows [r0,r0+16) = relu(bn2(x3)) @ w1^T + b1 =========
    {
        float* aT     = smem;           // [16][36]
        float* wT     = smem + 576;     // [32][260]
        float* ps     = smem + 8896;    // [4][256]
        float* ps2    = smem + 9920;    // [4][256]
        float* bn2raw = smem + 10944;   // 256
        float* mu2l   = smem + 11200;   // 128
        float* rs2l   = smem + 11328;   // 128
        {
            float s = 0.f;
#pragma unroll
            for (int r = 0; r < REP; ++r) s += aload(ws + OFF_STAT2 + r*256 + t);
            bn2raw[t] = s;
        }
        __syncthreads();
        if (t < DIM) {
            float mu = bn2raw[t]*invn;
            float var = fmaxf(bn2raw[DIM + t]*invn - mu*mu, 0.f);
            mu2l[t] = mu;
            rs2l[t] = rsqrtf(var + EPS);
        }
        __syncthreads();
        const float* x3 = ws + OFF_X3;
        float* o1 = ws + OFF_O1;
        int cg = t & 63;
        int rg = t >> 6;
        float acc[4][4];
#pragma unroll
        for (int a = 0; a < 4; ++a)
#pragma unroll
            for (int q = 0; q < 4; ++q) acc[a][q] = 0.f;
        int kk = t & 31;
        for (int k0 = 0; k0 < DIM; k0 += 32) {
            int k = k0 + kk;
            float mu = mu2l[k], rs = rs2l[k], gg = g2[k], bb = b2v[k];
#pragma unroll
            for (int j = 0; j < 2; ++j) {
                int row = (t >> 5) + j*8;
                float v = (x3[(r0+row)*DIM + k] - mu)*rs*gg + bb;
                aT[row*36 + kk] = fmaxf(v, 0.f);
            }
#pragma unroll
            for (int j = 0; j < 32; ++j) {
                int i = t + j*256;
                int kk2 = i & 31, c = i >> 5;
                wT[kk2*260 + c] = w1[c*DIM + k0 + kk2];
            }
            __syncthreads();
#pragma unroll
            for (int q4 = 0; q4 < 8; ++q4) {
                float4 av[4], wv[4];
#pragma unroll
                for (int rr = 0; rr < 4; ++rr)
                    av[rr] = *(const float4*)&aT[(rg*4+rr)*36 + q4*4];
#pragma unroll
                for (int q = 0; q < 4; ++q)
                    wv[q] = *(const float4*)&wT[(q4*4+q)*260 + cg*4];
#pragma unroll
                for (int rr = 0; rr < 4; ++rr) {
                    acc[rr][0] += av[rr].x*wv[0].x + av[rr].y*wv[1].x + av[rr].z*wv[2].x + av[rr].w*wv[3].x;
                    acc[rr][1] += av[rr].x*wv[0].y + av[rr].y*wv[1].y + av[rr].z*wv[2].y + av[rr].w*wv[3].y;
                    acc[rr][2] += av[rr].x*wv[0].z + av[rr].y*wv[1].z + av[rr].z*wv[2].z + av[rr].w*wv[3].z;
                    acc[rr][3] += av[rr].x*wv[0].w + av[rr].y*wv[1].w + av[rr].z*wv[2].w + av[rr].w*wv[3].w;
                }
            }
            __syncthreads();
        }
        int cbase = cg*4;
        float4 bv = *(const float4*)&b1v[cbase];
        float lv[4]  = {0,0,0,0};
        float lv2[4] = {0,0,0,0};
#pragma unroll
        for (int rr = 0; rr < 4; ++rr) {
            int row = r0 + rg*4 + rr;
            float o0 = acc[rr][0] + bv.x;
            float o1v = acc[rr][1] + bv.y;
            float o2 = acc[rr][2] + bv.z;
            float o3 = acc[rr][3] + bv.w;
            *(float4*)&o1[row*INTER + cbase] = make_float4(o0, o1v, o2, o3);
            lv[0]+=o0;  lv2[0]+=o0*o0;
            lv[1]+=o1v; lv2[1]+=o1v*o1v;
            lv[2]+=o2;  lv2[2]+=o2*o2;
            lv[3]+=o3;  lv2[3]+=o3*o3;
        }
        *(float4*)&ps[rg*256 + cbase]  = make_float4(lv[0], lv[1], lv[2], lv[3]);
        *(float4*)&ps2[rg*256 + cbase] = make_float4(lv2[0], lv2[1], lv2[2], lv2[3]);
        __syncthreads();
        if (t < INTER) {
            float s1 = ps[t] + ps[256+t] + ps[512+t] + ps[768+t];
            float s2 = ps2[t] + ps2[256+t] + ps2[512+t] + ps2[768+t];
            atomicAdd(&ws[OFF_STAT3 + (b & (REP-1))*512 + t], s1);
            atomicAdd(&ws[OFF_STAT3 + (b & (REP-1))*512 + INTER + t], s2);
        }
    }
    gbar(&bar[3]);

    // ===== phase 4: out rows [r0,r0+16) = relu(bn3(o1)) @ w2^T + b2 ========
    {
        float* raw  = smem;          // 512
        float* mu3l = smem + 512;    // 256
        float* rs3l = smem + 768;    // 256
        for (int tt = t; tt < 512; tt += 256) {
            float s = 0.f;
#pragma unroll
            for (int r = 0; r < REP; ++r) s += aload(ws + OFF_STAT3 + r*512 + tt);
            raw[tt] = s;
        }
        __syncthreads();
        {
            float mu = raw[t]*invn;
            float var = fmaxf(raw[256 + t]*invn - mu*mu, 0.f);
            mu3l[t] = mu;
            rs3l[t] = rsqrtf(var + EPS);
        }
        __syncthreads();
        float m3[4], rg3[4], b3q[4], w2q[4];
#pragma unroll
        for (int q = 0; q < 4; ++q) {
            int c = l*4 + q;
            m3[q] = mu3l[c];
            rg3[q] = rs3l[c]*g3[c];
            b3q[q] = b3[c];
            w2q[q] = w2[c];
        }
        float bias2 = b2s[0];
        const float4* o14 = (const float4*)(ws + OFF_O1);
#pragma unroll
        for (int j = 0; j < 4; ++j) {
            int row = r0 + w*4 + j;
            float4 vv = o14[row*64 + l];
            float s = 0.f;
#pragma unroll
            for (int q = 0; q < 4; ++q) {
                float val = (((const float*)&vv)[q] - m3[q])*rg3[q] + b3q[q];
                val = fmaxf(val, 0.f);
                s += val * w2q[q];
            }
#pragma unroll
            for (int m = 32; m >= 1; m >>= 1) s += __shfl_xor(s, m, 64);
            if (l == 0) out[row] = s + bias2;
        }
    }
}

extern "C" void kernel_launch(void* const* d_in, const int* in_sizes, int n_in,
                              void* d_out, int out_size, void* d_ws, size_t ws_size,
                              hipStream_t stream) {
    const float* x        = (const float*)d_in[0];
    const float* emb      = (const float*)d_in[1];
    const float* w_lin    = (const float*)d_in[2];
    const float* att_i    = (const float*)d_in[3];
    const float* att_j    = (const float*)d_in[4];
    const float* att_em_i = (const float*)d_in[5];
    const float* att_em_j = (const float*)d_in[6];
    const float* g_bias   = (const float*)d_in[7];
    const float* bn1_g    = (const float*)d_in[8];
    const float* bn1_b    = (const float*)d_in[9];
    const float* bn2_g    = (const float*)d_in[10];
    const float* bn2_b    = (const float*)d_in[11];
    const float* bn3_g    = (const float*)d_in[12];
    const float* bn3_b    = (const float*)d_in[13];
    const float* w1       = (const float*)d_in[14];
    const float* b1       = (const float*)d_in[15];
    const float* w2       = (const float*)d_in[16];
    const float* b2       = (const float*)d_in[17];
    float* out = (float*)d_out;
    float* ws  = (float*)d_ws;
    int*   idx = (int*)(ws + OFF_IDX);

    // zero stat accumulators + barrier counters
    hipMemsetAsync((void*)(ws + OFF_STATA), 0, ZERO_BYTES, stream);

    k_fused<<<NBLK, 256, 0, stream>>>(x, emb, w_lin, att_i, att_j, att_em_i,
                                      att_em_j, g_bias, bn1_g, bn1_b, bn2_g, bn2_b,
                                      bn3_g, bn3_b, w1, b1, w2, b2, ws, idx, out);
}

// Round 9
// 182.180 us; speedup vs baseline: 1.6343x; 1.2189x over previous
//
#include <hip/hip_runtime.h>

#define NODE 100
#define BATCH 64
#define DIM 128
#define IN_DIM 5
#define TOPK 30
#define INTER 256
#define NB (BATCH*NODE)   /* 6400 */
#define EPS 1e-5f
#define SLOPE 0.2f
#define REP 16            /* stat replicas */
#define NBLK 400          /* blocks; block b owns rows [16b,16b+16) */
#define ROWS 16
#define NTHR 512
#define GRPS 16
#define GRPSZ (NBLK/GRPS) /* 25 */

// scratch float offsets
#define OFF_AGG    0
#define OFF_X3     819200
#define OFF_O1     1638400
#define OFF_U      3276800   /* u_i[0..4], u_j[5..9] */
#define OFF_EI     3276816
#define OFF_EJ     3276928
#define OFF_STATA  3277056   /* REP*32  */
#define OFF_STAT2  3277568   /* REP*256 */
#define OFF_STAT3  3281664   /* REP*512 */
#define OFF_BAR    3289856   /* 4 barriers x 1088 ints */
#define OFF_IDX    3294208   /* 3000 ints */
#define ZERO_BYTES ((OFF_IDX - OFF_STATA) * 4)

__device__ __forceinline__ float aload(const float* p) {
    return __hip_atomic_load(p, __ATOMIC_RELAXED, __HIP_MEMORY_SCOPE_AGENT);
}
__device__ __forceinline__ void astore(float* p, float v) {
    __hip_atomic_store(p, v, __ATOMIC_RELAXED, __HIP_MEMORY_SCOPE_AGENT);
}
__device__ __forceinline__ int aloadi(const int* p) {
    return __hip_atomic_load(p, __ATOMIC_RELAXED, __HIP_MEMORY_SCOPE_AGENT);
}
__device__ __forceinline__ void astorei(int* p, int v) {
    __hip_atomic_store(p, v, __ATOMIC_RELAXED, __HIP_MEMORY_SCOPE_AGENT);
}

// hierarchical grid barrier: 16 spread arrive lines -> root -> release flag.
// Spinners poll the flag READ-ONLY (no RMW serialization).
__device__ __forceinline__ void gbar(int* base) {
    __syncthreads();
    if (threadIdx.x == 0) {
        int g = blockIdx.x & (GRPS-1);
        int* sub  = base + g*64;      // 256B apart -> separate lines
        int* root = base + 1024;
        int* flag = base + 1025;
        int v = __hip_atomic_fetch_add(sub, 1, __ATOMIC_RELAXED, __HIP_MEMORY_SCOPE_AGENT);
        if (v == GRPSZ-1) {
            int r = __hip_atomic_fetch_add(root, 1, __ATOMIC_RELAXED, __HIP_MEMORY_SCOPE_AGENT);
            if (r == GRPS-1)
                __hip_atomic_store(flag, 1, __ATOMIC_RELAXED, __HIP_MEMORY_SCOPE_AGENT);
        }
        while (!__hip_atomic_load(flag, __ATOMIC_RELAXED, __HIP_MEMORY_SCOPE_AGENT))
            __builtin_amdgcn_s_sleep(1);
    }
    __syncthreads();
}

__global__ __launch_bounds__(NTHR, 4) void k_fused(
        const float* __restrict__ x, const float* __restrict__ emb,
        const float* __restrict__ w_lin,
        const float* __restrict__ att_i, const float* __restrict__ att_j,
        const float* __restrict__ att_em_i, const float* __restrict__ att_em_j,
        const float* __restrict__ g_bias,
        const float* __restrict__ g1, const float* __restrict__ b1,
        const float* __restrict__ g2, const float* __restrict__ b2v,
        const float* __restrict__ g3, const float* __restrict__ b3,
        const float* __restrict__ w1, const float* __restrict__ b1v,
        const float* __restrict__ w2, const float* __restrict__ b2s,
        float* __restrict__ ws, int* __restrict__ idx, float* __restrict__ out) {
    __shared__ __align__(16) float smem[13504];   // 54 KB max (phase 3)
    int* bar = (int*)(ws + OFF_BAR);
    const int b = blockIdx.x, t = threadIdx.x, w = t >> 6, l = t & 63;
    const float invn = 1.f/(float)NB;
    const int r0 = b * ROWS;
    const int fb = r0 / NODE, lb = (r0 + ROWS - 1) / NODE;

    // ===== phase 0: topk (b<13, 8 targets each) / scalars (b==13) / prefetch
    if (b < 13) {
        float* eT = smem;                  // [32][101]
        int i = b*8 + w;
        bool act = (i < NODE);
        int j0 = l, j1 = l + 64;
        bool ok1 = (j1 < NODE);
        float d0 = 0.f, d1 = 0.f, ni = 0.f, n0 = 0.f, n1 = 0.f;
        for (int kc = 0; kc < 4; ++kc) {
            __syncthreads();
            for (int ii = t; ii < 3200; ii += NTHR) {
                int n = ii >> 5, d = ii & 31;
                eT[d*101 + n] = emb[n*DIM + kc*32 + d];
            }
            __syncthreads();
            if (act) {
#pragma unroll
                for (int dd = 0; dd < 32; ++dd) {
                    float ei = eT[dd*101 + i];
                    float a0 = eT[dd*101 + j0];
                    ni += ei*ei; d0 += ei*a0; n0 += a0*a0;
                    if (ok1) { float a1v = eT[dd*101 + j1]; d1 += ei*a1v; n1 += a1v*a1v; }
                }
            }
        }
        if (act) {
            float sni = sqrtf(ni);
            float c0 = d0 / (sni * sqrtf(n0));
            float c1 = ok1 ? d1 / (sni * sqrtf(n1)) : -INFINITY;
            for (int r = 0; r < TOPK; ++r) {
                float bv; int bi;
                if (c1 > c0) { bv = c1; bi = j1; } else { bv = c0; bi = j0; }
#pragma unroll
                for (int m = 32; m >= 1; m >>= 1) {
                    float ov = __shfl_xor(bv, m, 64);
                    int   oi = __shfl_xor(bi, m, 64);
                    if (ov > bv || (ov == bv && oi < bi)) { bv = ov; bi = oi; }
                }
                if (l == 0) astorei(idx + i*TOPK + r, bi);
                if (bi == j0) c0 = -INFINITY;
                if (bi == j1) c1 = -INFINITY;
            }
        }
    } else if (b == 13) {
        float* Pi = smem;            // [5][128]
        float* Pj = smem + 640;
        if (t < DIM) {
            float wi = att_i[t], wj = att_j[t];
#pragma unroll
            for (int c = 0; c < IN_DIM; ++c) {
                float wl = w_lin[t*IN_DIM + c];
                Pi[c*128 + t] = wl*wi;
                Pj[c*128 + t] = wl*wj;
            }
        }
        __syncthreads();
        if (t < 10) {
            int c = (t < 5) ? t : t - 5;
            const float* P = (t < 5) ? Pi : Pj;
            float s = 0.f;
            for (int k = 0; k < DIM; ++k) s += P[c*128 + k];
            astore(ws + OFF_U + t, s);
        }
        float a0 = att_em_i[l], a1 = att_em_i[l+64];
        float b0 = att_em_j[l], b1v_ = att_em_j[l+64];
        int nend = w*13 + 13; if (nend > NODE) nend = NODE;
        for (int n = w*13; n < nend; ++n) {
            float v0 = emb[n*DIM + l], v1 = emb[n*DIM + l + 64];
            float pi = v0*a0 + v1*a1;
            float pj = v0*b0 + v1*b1v_;
#pragma unroll
            for (int m = 32; m >= 1; m >>= 1) {
                pi += __shfl_xor(pi, m, 64);
                pj += __shfl_xor(pj, m, 64);
            }
            if (l == 0) { astore(ws + OFF_EI + n, pi); astore(ws + OFF_EJ + n, pj); }
        }
    } else {
        // prefetch phase-1 x slabs into the phase-1 LDS layout (input-only)
        float* xl = smem + 16;
        for (int i = t; i < 500; i += NTHR) {
            xl[i]       = x[fb*500 + i];
            xl[500 + i] = x[lb*500 + i];
        }
    }
    gbar(bar);

    // ===== phase 1: agg rows [r0,r0+16) (5-dim attention) + bn1 moments ====
    {
        float* ul   = smem;                // 16
        float* xl   = smem + 16;           // [2][500]
        float* sjl  = smem + 1016;         // [2][100]
        float* eil  = smem + 1216;         // [16]
        int*   idl  = (int*)(smem + 1232); // [16][30]
        float* psum = smem + 1712;         // [8][20]
        float* agg  = ws + OFF_AGG;
        if (b < 14) {
            for (int i = t; i < 500; i += NTHR) {
                xl[i]       = x[fb*500 + i];
                xl[500 + i] = x[lb*500 + i];
            }
        }
        if (t < 10) ul[t] = aload(ws + OFF_U + t);
        if (t < ROWS) eil[t] = aload(ws + OFF_EI + (r0 + t) % NODE);
        if (t < ROWS*TOPK)
            idl[t] = aloadi(idx + ((r0 + t/TOPK) % NODE)*TOPK + t % TOPK);
        __syncthreads();
        if (t < 200) {
            int bb = t / 100, n = t % 100;
            float s = aload(ws + OFF_EJ + n);
#pragma unroll
            for (int c = 0; c < IN_DIM; ++c) s += xl[bb*500 + n*IN_DIM + c] * ul[5 + c];
            sjl[t] = s;
        }
        __syncthreads();
        float wl0[IN_DIM], wl1[IN_DIM];
#pragma unroll
        for (int c = 0; c < IN_DIM; ++c) {
            wl0[c] = w_lin[l*IN_DIM + c];
            wl1[c] = w_lin[(l+64)*IN_DIM + c];
        }
        float gb0 = g_bias[l], gb1 = g_bias[l+64];
        float S0=0,S1=0,S2=0,S3=0,S4=0;
        float M[15];
#pragma unroll
        for (int m = 0; m < 15; ++m) M[m] = 0.f;
        for (int rr = w; rr < ROWS; rr += 8) {
            int row = r0 + rr;
            int bb = (row / NODE == fb) ? 0 : 1;
            int node = row % NODE;
            float si = eil[rr];
#pragma unroll
            for (int c = 0; c < IN_DIM; ++c) si += xl[bb*500 + node*IN_DIM + c] * ul[c];
            float mx = -INFINITY;
#pragma unroll
            for (int r = 0; r < TOPK; ++r) {
                int s = idl[rr*TOPK + r];
                float a = si + sjl[bb*100 + s];
                a = (a > 0.f) ? a : SLOPE*a;
                mx = fmaxf(mx, a);
            }
            float ssum = 0.f, x0=0,x1=0,x2=0,x3v=0,x4=0;
#pragma unroll
            for (int r = 0; r < TOPK; ++r) {
                int s = idl[rr*TOPK + r];
                float a = si + sjl[bb*100 + s];
                a = (a > 0.f) ? a : SLOPE*a;
                float e = expf(a - mx);
                ssum += e;
                const float* xr = &xl[bb*500 + s*IN_DIM];
                x0 += e*xr[0]; x1 += e*xr[1]; x2 += e*xr[2]; x3v += e*xr[3]; x4 += e*xr[4];
            }
            float inv = 1.f/(ssum + 1e-16f);
            float y0=x0*inv, y1=x1*inv, y2=x2*inv, y3=x3v*inv, y4=x4*inv;
            float o0 = y0*wl0[0]+y1*wl0[1]+y2*wl0[2]+y3*wl0[3]+y4*wl0[4] + gb0;
            float o1 = y0*wl1[0]+y1*wl1[1]+y2*wl1[2]+y3*wl1[3]+y4*wl1[4] + gb1;
            agg[row*DIM + l]      = o0;
            agg[row*DIM + l + 64] = o1;
            S0+=y0; S1+=y1; S2+=y2; S3+=y3; S4+=y4;
            M[0]+=y0*y0; M[1]+=y0*y1; M[2]+=y0*y2; M[3]+=y0*y3; M[4]+=y0*y4;
            M[5]+=y1*y1; M[6]+=y1*y2; M[7]+=y1*y3; M[8]+=y1*y4;
            M[9]+=y2*y2; M[10]+=y2*y3; M[11]+=y2*y4;
            M[12]+=y3*y3; M[13]+=y3*y4; M[14]+=y4*y4;
        }
        __syncthreads();
        if (l == 0) {
            psum[w*20+0]=S0; psum[w*20+1]=S1; psum[w*20+2]=S2; psum[w*20+3]=S3; psum[w*20+4]=S4;
#pragma unroll
            for (int m = 0; m < 15; ++m) psum[w*20+5+m] = M[m];
        }
        __syncthreads();
        if (t < 20) {
            float p = 0.f;
#pragma unroll
            for (int q = 0; q < 8; ++q) p += psum[q*20 + t];
            atomicAdd(&ws[OFF_STATA + (b & (REP-1))*32 + t], p);
        }
    }
    gbar(bar + 1088);

    // ===== phase 2: x3 rows = relu(bn1(agg))*emb + bn2 sums ================
    {
        float* A  = smem;            // 20
        float* pv = smem + 32;       // [16][128]
        float* pq = smem + 2080;     // [16][128]
        if (t < 20) {
            float s = 0.f;
#pragma unroll
            for (int r = 0; r < REP; ++r) s += aload(ws + OFF_STATA + r*32 + t);
            A[t] = s;
        }
        __syncthreads();
        int cq = (t & 31) * 4;
        float muq[4], rsg[4], bq[4];
#pragma unroll
        for (int q = 0; q < 4; ++q) {
            int c = cq + q;
            float w0 = w_lin[c*IN_DIM+0], w1v = w_lin[c*IN_DIM+1], w2v = w_lin[c*IN_DIM+2],
                  w3 = w_lin[c*IN_DIM+3], w4 = w_lin[c*IN_DIM+4];
            float Sv = A[0]*w0 + A[1]*w1v + A[2]*w2v + A[3]*w3 + A[4]*w4;
            float Q  = w0*w0*A[5] + w1v*w1v*A[10] + w2v*w2v*A[14] + w3*w3*A[17] + w4*w4*A[19]
                     + 2.f*(w0*w1v*A[6] + w0*w2v*A[7] + w0*w3*A[8] + w0*w4*A[9]
                          + w1v*w2v*A[11] + w1v*w3*A[12] + w1v*w4*A[13]
                          + w2v*w3*A[15] + w2v*w4*A[16] + w3*w4*A[18]);
            float mv = Sv*invn;
            float mu = mv + g_bias[c];
            float var = fmaxf(Q*invn - mv*mv, 0.f);
            float rs = rsqrtf(var + EPS);
            muq[q] = mu; rsg[q] = rs*g1[c]; bq[q] = b1[c];
        }
        const float4* agg4 = (const float4*)(ws + OFF_AGG);
        const float4* emb4 = (const float4*)emb;
        float4* x34 = (float4*)(ws + OFF_X3);
        int i4 = b*512 + t;
        int row = i4 >> 5;
        int node = row % NODE;
        float4 av = agg4[i4];
        float4 ev = emb4[node*32 + (t & 31)];
        float o[4];
#pragma unroll
        for (int q = 0; q < 4; ++q) {
            float val = (((const float*)&av)[q] - muq[q])*rsg[q] + bq[q];
            val = fmaxf(val, 0.f);
            o[q] = val * ((const float*)&ev)[q];
        }
        x34[i4] = make_float4(o[0], o[1], o[2], o[3]);
        int g = t >> 5;
        *(float4*)&pv[g*128 + cq] = make_float4(o[0], o[1], o[2], o[3]);
        *(float4*)&pq[g*128 + cq] = make_float4(o[0]*o[0], o[1]*o[1], o[2]*o[2], o[3]*o[3]);
        __syncthreads();
        if (t < DIM) {
            float s1 = 0.f, s2 = 0.f;
#pragma unroll
            for (int r = 0; r < 16; ++r) { s1 += pv[r*128 + t]; s2 += pq[r*128 + t]; }
            atomicAdd(&ws[OFF_STAT2 + (b & (REP-1))*256 + t], s1);
            atomicAdd(&ws[OFF_STAT2 + (b & (REP-1))*256 + DIM + t], s2);
        }
    }
    gbar(bar + 2*1088);

    // ===== phase 3: o1 rows = relu(bn2(x3)) @ w1^T + b1 + bn3 sums =========
    {
        float* aT     = smem;           // [16][36]  = 576
        float* wT     = smem + 576;     // [32][260] = 8320
        float* ps     = smem + 8896;    // [8][256]
        float* ps2    = smem + 10944;   // [8][256]
        float* bn2raw = smem + 12992;   // 256
        float* mu2l   = smem + 13248;   // 128
        float* rs2l   = smem + 13376;   // 128
        if (t < 256) {
            float s = 0.f;
#pragma unroll
            for (int r = 0; r < REP; ++r) s += aload(ws + OFF_STAT2 + r*256 + t);
            bn2raw[t] = s;
        }
        __syncthreads();
        if (t < DIM) {
            float mu = bn2raw[t]*invn;
            float var = fmaxf(bn2raw[DIM + t]*invn - mu*mu, 0.f);
            mu2l[t] = mu;
            rs2l[t] = rsqrtf(var + EPS);
        }
        __syncthreads();
        const float* x3 = ws + OFF_X3;
        float* o1 = ws + OFF_O1;
        int cg = t & 63;
        int rg = t >> 6;
        float acc[2][4];
#pragma unroll
        for (int a = 0; a < 2; ++a)
#pragma unroll
            for (int q = 0; q < 4; ++q) acc[a][q] = 0.f;
        int kk = t & 31;
        for (int k0 = 0; k0 < DIM; k0 += 32) {
            {
                int row = t >> 5;         // 0..15
                int k = k0 + kk;
                float v = (x3[(r0+row)*DIM + k] - mu2l[k])*rs2l[k]*g2[k] + b2v[k];
                aT[row*36 + kk] = fmaxf(v, 0.f);
            }
            for (int i = t; i < 8192; i += NTHR) {
                int kk2 = i & 31, c = i >> 5;
                wT[kk2*260 + c] = w1[c*DIM + k0 + kk2];
            }
            __syncthreads();
#pragma unroll
            for (int q4 = 0; q4 < 8; ++q4) {
                float4 av[2], wv[4];
#pragma unroll
                for (int rr = 0; rr < 2; ++rr)
                    av[rr] = *(const float4*)&aT[(rg*2+rr)*36 + q4*4];
#pragma unroll
                for (int q = 0; q < 4; ++q)
                    wv[q] = *(const float4*)&wT[(q4*4+q)*260 + cg*4];
#pragma unroll
                for (int rr = 0; rr < 2; ++rr) {
                    acc[rr][0] += av[rr].x*wv[0].x + av[rr].y*wv[1].x + av[rr].z*wv[2].x + av[rr].w*wv[3].x;
                    acc[rr][1] += av[rr].x*wv[0].y + av[rr].y*wv[1].y + av[rr].z*wv[2].y + av[rr].w*wv[3].y;
                    acc[rr][2] += av[rr].x*wv[0].z + av[rr].y*wv[1].z + av[rr].z*wv[2].z + av[rr].w*wv[3].z;
                    acc[rr][3] += av[rr].x*wv[0].w + av[rr].y*wv[1].w + av[rr].z*wv[2].w + av[rr].w*wv[3].w;
                }
            }
            __syncthreads();
        }
        int cbase = cg*4;
        float4 bv = *(const float4*)&b1v[cbase];
        float lv[4]  = {0,0,0,0};
        float lv2[4] = {0,0,0,0};
#pragma unroll
        for (int rr = 0; rr < 2; ++rr) {
            int row = r0 + rg*2 + rr;
            float o0 = acc[rr][0] + bv.x;
            float o1v = acc[rr][1] + bv.y;
            float o2 = acc[rr][2] + bv.z;
            float o3 = acc[rr][3] + bv.w;
            *(float4*)&o1[row*INTER + cbase] = make_float4(o0, o1v, o2, o3);
            lv[0]+=o0;  lv2[0]+=o0*o0;
            lv[1]+=o1v; lv2[1]+=o1v*o1v;
            lv[2]+=o2;  lv2[2]+=o2*o2;
            lv[3]+=o3;  lv2[3]+=o3*o3;
        }
        *(float4*)&ps[rg*256 + cbase]  = make_float4(lv[0], lv[1], lv[2], lv[3]);
        *(float4*)&ps2[rg*256 + cbase] = make_float4(lv2[0], lv2[1], lv2[2], lv2[3]);
        __syncthreads();
        if (t < INTER) {
            float s1 = 0.f, s2 = 0.f;
#pragma unroll
            for (int q = 0; q < 8; ++q) { s1 += ps[q*256 + t]; s2 += ps2[q*256 + t]; }
            atomicAdd(&ws[OFF_STAT3 + (b & (REP-1))*512 + t], s1);
            atomicAdd(&ws[OFF_STAT3 + (b & (REP-1))*512 + INTER + t], s2);
        }
    }
    gbar(bar + 3*1088);

    // ===== phase 4: out rows = relu(bn3(o1)) @ w2^T + b2 ===================
    {
        float* raw  = smem;          // 512
        float* mu3l = smem + 512;    // 256
        float* rs3l = smem + 768;    // 256
        {
            float s = 0.f;
#pragma unroll
            for (int r = 0; r < REP; ++r) s += aload(ws + OFF_STAT3 + r*512 + t);
            raw[t] = s;
        }
        __syncthreads();
        if (t < INTER) {
            float mu = raw[t]*invn;
            float var = fmaxf(raw[256 + t]*invn - mu*mu, 0.f);
            mu3l[t] = mu;
            rs3l[t] = rsqrtf(var + EPS);
        }
        __syncthreads();
        float m3[4], rg3[4], b3q[4], w2q[4];
#pragma unroll
        for (int q = 0; q < 4; ++q) {
            int c = l*4 + q;
            m3[q] = mu3l[c];
            rg3[q] = rs3l[c]*g3[c];
            b3q[q] = b3[c];
            w2q[q] = w2[c];
        }
        float bias2 = b2s[0];
        const float4* o14 = (const float4*)(ws + OFF_O1);
#pragma unroll
        for (int j = 0; j < 2; ++j) {
            int row = r0 + w*2 + j;
            float4 vv = o14[row*64 + l];
            float s = 0.f;
#pragma unroll
            for (int q = 0; q < 4; ++q) {
                float val = (((const float*)&vv)[q] - m3[q])*rg3[q] + b3q[q];
                val = fmaxf(val, 0.f);
                s += val * w2q[q];
            }
#pragma unroll
            for (int m = 32; m >= 1; m >>= 1) s += __shfl_xor(s, m, 64);
            if (l == 0) out[row] = s + bias2;
        }
    }
}

extern "C" void kernel_launch(void* const* d_in, const int* in_sizes, int n_in,
                              void* d_out, int out_size, void* d_ws, size_t ws_size,
                              hipStream_t stream) {
    const float* x        = (const float*)d_in[0];
    const float* emb      = (const float*)d_in[1];
    const float* w_lin    = (const float*)d_in[2];
    const float* att_i    = (const float*)d_in[3];
    const float* att_j    = (const float*)d_in[4];
    const float* att_em_i = (const float*)d_in[5];
    const float* att_em_j = (const float*)d_in[6];
    const float* g_bias   = (const float*)d_in[7];
    const float* bn1_g    = (const float*)d_in[8];
    const float* bn1_b    = (const float*)d_in[9];
    const float* bn2_g    = (const float*)d_in[10];
    const float* bn2_b    = (const float*)d_in[11];
    const float* bn3_g    = (const float*)d_in[12];
    const float* bn3_b    = (const float*)d_in[13];
    const float* w1       = (const float*)d_in[14];
    const float* b1       = (const float*)d_in[15];
    const float* w2       = (const float*)d_in[16];
    const float* b2       = (const float*)d_in[17];
    float* out = (float*)d_out;
    float* ws  = (float*)d_ws;
    int*   idx = (int*)(ws + OFF_IDX);

    hipMemsetAsync((void*)(ws + OFF_STATA), 0, ZERO_BYTES, stream);

    k_fused<<<NBLK, NTHR, 0, stream>>>(x, emb, w_lin, att_i, att_j, att_em_i,
                                       att_em_j, g_bias, bn1_g, bn1_b, bn2_g, bn2_b,
                                       bn3_g, bn3_b, w1, b1, w2, b2, ws, idx, out);
}